// Round 7
// baseline (632.087 us; speedup 1.0000x reference)
//
#include <hip/hip_runtime.h>

// SSN superpixel EM, MI355X. B=4, H=W=256, C=20, KG=16 (K=256), CELL=16, 10 EM iters.
// Exploits 9-neighborhood sparsity: posteriors are exactly 0 outside it (exp underflow).
// v7: persistent cooperative kernel, per-slot dataflow, NO STATS ATOMICS.
//   - v2..v6 post-mortem: FETCH ~490MB constant across 4 sync schemes -> excess HBM traffic
//     is structural: 1.94M memory-side atomicAdd RMWs (189/block/iter) + zero phase.
//   - v7 M-step: each block writes its 189 partials as ONE contiguous 756B plain system
//     store into its own P area. Slot owner waits cc[k] == g*cnt(k) (9 tiny atomics/block),
//     gathers <=9 contributors' 21-float runs (coalesced), sums in LDS, writes S_g[k],
//     publishes rc[k]=g+1 (single-writer plain store). Consumers poll 9 rc words.
//   - Generation-parity double buffering for S and P replaces the triple-buffer + zeroing.
//     Reuse safety: writer of P[g&1][m] requires rc>=g on its 3x3 (so owner k finished
//     reading P[(g-2)&1][m] before publishing rc[k]=g-1). Writer of S[g&1][k] requires
//     cc[k]=g*cnt (so all stagers of S[g-2][k] - who are exactly k's contributors - are
//     past their gen-(g-1) partial writes, hence past their S[g-2] reads).
//   - Ordering: __syncthreads() drains vmcnt for ALL waves before any signal (proven v4-v6).
//   - Spin timeouts kept: wrong theory -> clean numeric fail, not hang.

#define NBATCH 4
#define WIMG   256
#define NC     20      // feature channels
#define NCS    21      // channels + colsum slot
#define NKG    16
#define NK     256
#define NPIX   65536
#define CELLSZ 16
#define LDST   260     // LDS row stride (floats), 16B-aligned rows
#define NBLK   (NBATCH * NK)   // 1024 blocks, 4/CU
#define CPAD   64      // counter padding in u32 words (256 B per counter line)
#define SB     ((size_t)NBATCH * NK * NCS)   // one S buffer: 21504 floats
#define PBLK   (9 * NCS)                     // 189 partials per block

typedef float nfloat4 __attribute__((ext_vector_type(4)));  // native vec for nontemporal builtin

__device__ __forceinline__ float dot4f(const float4 a, const float4 b) {
    return fmaf(a.x, b.x, fmaf(a.y, b.y, fmaf(a.z, b.z, a.w * b.w)));
}

// SYSTEM scope: sc0+sc1 -> bypass L1 and (non-cross-XCD-coherent) L2.
__device__ __forceinline__ float sys_load(const float* p) {
    return __hip_atomic_load(p, __ATOMIC_RELAXED, __HIP_MEMORY_SCOPE_SYSTEM);
}
__device__ __forceinline__ void sys_store(float* p, float v) {
    __hip_atomic_store(p, v, __ATOMIC_RELAXED, __HIP_MEMORY_SCOPE_SYSTEM);
}
__device__ __forceinline__ unsigned sys_loadu(const unsigned* p) {
    return __hip_atomic_load(p, __ATOMIC_RELAXED, __HIP_MEMORY_SCOPE_SYSTEM);
}
__device__ __forceinline__ void sys_storeu(unsigned* p, unsigned v) {
    __hip_atomic_store(p, v, __ATOMIC_RELAXED, __HIP_MEMORY_SCOPE_SYSTEM);
}

// Consumers: poll rc of the 9 neighbor slots for >= tgt (rc[k]=g+1 means S_g[k] ready).
__device__ __forceinline__ void wait_rc(const unsigned* rc, unsigned tgt,
                                        int b, int cy, int cx, int t) {
    if (t < 9) {
        int ky = cy + t / 3 - 1, kx = cx + (t % 3) - 1;
        if (ky >= 0 && ky < NKG && kx >= 0 && kx < NKG) {
            const unsigned* p = rc + (size_t)(b * NK + ky * NKG + kx) * CPAD;
            unsigned long long t0 = __builtin_amdgcn_s_memrealtime();
            while (sys_loadu(p) < tgt) {
                __builtin_amdgcn_s_sleep(2);
                if (__builtin_amdgcn_s_memrealtime() - t0 > 10000000ull) break;  // fail clean
            }
        }
    }
    __syncthreads();
}

__device__ __forceinline__ void load_feat(const float* __restrict__ feat, int b, int n, float f[NC]) {
    const float4* fp = (const float4*)(feat + ((size_t)b * NPIX + n) * NC);  // 80B/pixel, 16B aligned
    #pragma unroll
    for (int i = 0; i < 5; ++i) {
        float4 v = fp[i];
        f[4 * i + 0] = v.x; f[4 * i + 1] = v.y; f[4 * i + 2] = v.z; f[4 * i + 3] = v.w;
    }
}

// Stage this block's 3x3 neighborhood stats into LDS; derive per-neighbor uniform
// coefficients so per-lane a[j] = rqs[j].x * dot(f, S_j) + rqs[j].y.
__device__ __forceinline__ void stage_neigh(const float* __restrict__ Sprev, int b, int cy, int cx,
                                            int t, float (*sM)[24], float (*rqs)[2]) {
    if (t < 189) {
        int j = t / 21, c = t - 21 * j;
        int ky = cy + j / 3 - 1, kx = cx + (j % 3) - 1;
        float v = 0.0f;
        if (ky >= 0 && ky < NKG && kx >= 0 && kx < NKG)
            v = sys_load(&Sprev[((size_t)(b * NK + ky * NKG + kx)) * NCS + c]);
        sM[j][c] = v;
    }
    __syncthreads();
    if (t < 9) {
        int ky = cy + t / 3 - 1, kx = cx + (t % 3) - 1;
        bool ok = (ky >= 0 && ky < NKG && kx >= 0 && kx < NKG);
        float ssq = 0.f;
        #pragma unroll
        for (int cq = 0; cq < 5; ++cq) {
            float4 sv = *((const float4*)&sM[t][4 * cq]);
            ssq += dot4f(sv, sv);
        }
        float r = 1.0f / fmaxf(sM[t][NC], 1e-12f);
        // -dist + feat_sq = 2*f.mean - ||mean||^2 ; invalid neighbors pinned to -1e30
        rqs[t][0] = ok ? 2.0f * r : 0.0f;
        rqs[t][1] = ok ? -(r * r) * ssq : -1e30f;
    }
    __syncthreads();
}

// Per-pixel softmax over 9 neighbors from staged LDS stats.
__device__ __forceinline__ void e_step_lds(const float f[NC], const float (*sM)[24],
                                           const float (*rqs)[2], float p[9]) {
    float a[9];
    float amax = -1e30f;
    #pragma unroll
    for (int j = 0; j < 9; ++j) {
        float dots = 0.f;
        #pragma unroll
        for (int cq = 0; cq < 5; ++cq) {
            float4 sv = *((const float4*)&sM[j][4 * cq]);   // ds_read_b128, broadcast
            dots = fmaf(f[4 * cq + 0], sv.x,
                   fmaf(f[4 * cq + 1], sv.y,
                   fmaf(f[4 * cq + 2], sv.z,
                   fmaf(f[4 * cq + 3], sv.w, dots))));
        }
        float2 rv = *((const float2*)rqs[j]);
        a[j] = fmaf(rv.x, dots, rv.y);
        amax = fmaxf(amax, a[j]);
    }
    float esum = 0.f;
    #pragma unroll
    for (int j = 0; j < 9; ++j) {
        float e = (a[j] > -1e29f) ? __expf(a[j] - amax) : 0.0f;
        p[j] = e;
        esum += e;
    }
    float inv = 1.0f / esum;
    #pragma unroll
    for (int j = 0; j < 9; ++j) p[j] *= inv;
}

#define NZLINES (2 * NBLK)   // rc lines + cc lines
__global__ void k_zero_ctr(unsigned* ctr) {
    int i = blockIdx.x * 256 + threadIdx.x;
    if (i < NZLINES) ctr[(size_t)i * CPAD] = 0u;   // only word 0 of each line is used
}

// Persistent fused kernel: init mean + 9 EM iterations + final dense output.
// Grid must be exactly NBATCH*NK = 1024 blocks (4 blocks/CU), launched cooperatively.
__global__ __launch_bounds__(256, 4) void k_fused(const float* __restrict__ feat,
                                                  float* __restrict__ Sbuf,   // [2][B*K][21]
                                                  float* __restrict__ Pp,     // [2][NBLK][9][21]
                                                  unsigned* __restrict__ rc,  // [NBLK] padded
                                                  unsigned* __restrict__ cc,  // [NBLK] padded
                                                  float* __restrict__ out) {
    __shared__ float fT[NCS * LDST];     // [c][n], row 20 = ones (colsum)
    __shared__ float pT[9 * LDST];       // [j][n]
    __shared__ float part[21 * 8 * 9];   // [tile][kid][3x3]; reused as gather buf [9][21]
    __shared__ float sM[9][24];          // staged neighbor stats, 16B-aligned rows
    __shared__ float rqs[9][2];          // per-neighbor (2/col, -||S||^2/col^2)

    int blk = blockIdx.x;
    int b = blk >> 8, k0 = blk & 255;
    int cy = k0 >> 4, cx = k0 & 15;
    int t = threadIdx.x;
    int ly = t >> 4, lx = t & 15;
    int n = (cy * CELLSZ + ly) * WIMG + cx * CELLSZ + lx;
    int slot = b * NK + k0;
    int cnt_k = (1 + (cy > 0) + (cy < NKG - 1)) * (1 + (cx > 0) + (cx < NKG - 1));

    float f[NC];
    load_feat(feat, b, n, f);
    #pragma unroll
    for (int c = 0; c < NC; ++c) fT[c * LDST + t] = f[c];
    fT[NC * LDST + t] = 1.0f;
    __syncthreads();

    // ---- init: S_0 = per-cell feature sums (col = 256), into Sbuf parity 0 ----
    if (t < NCS) {
        float s;
        if (t == NC) {
            s = 256.0f;
        } else {
            s = 0.f;
            const float4* row = (const float4*)&fT[t * LDST];
            #pragma unroll 4
            for (int i = 0; i < 64; ++i) { float4 v = row[i]; s += v.x + v.y + v.z + v.w; }
        }
        sys_store(&Sbuf[(size_t)slot * NCS + t], s);
    }
    __syncthreads();                        // drain S_0 stores
    if (t == 0) sys_storeu(rc + (size_t)slot * CPAD, 1u);   // S_0 ready

    for (unsigned g = 1; g <= 9; ++g) {
        const float* Sprev = Sbuf + (size_t)((g - 1) & 1) * SB;
        float*       Snew  = Sbuf + (size_t)(g & 1) * SB;
        float*       Pcur  = Pp + (size_t)(g & 1) * NBLK * PBLK;

        // 1. wait: my 3x3 S_{g-1} published
        wait_rc(rc, g, b, cy, cx, t);
        // 2. stage + coefficients
        stage_neigh(Sprev, b, cy, cx, t, sM, rqs);

        // 3. E-step
        float p[9];
        e_step_lds(f, sM, rqs, p);
        #pragma unroll
        for (int j = 0; j < 9; ++j) pT[j * LDST + t] = p[j];
        __syncthreads();

        // 4. Tiled [9x256]x[256x21] reduction: 21 (3j x 3c) tiles x 8 K-splits = 168 threads.
        if (t < 168) {
            int tile = t >> 3, kid = t & 7;
            int j0 = (tile / 7) * 3, c0 = (tile % 7) * 3;
            float acc[3][3] = {};
            #pragma unroll
            for (int ch = 0; ch < 8; ++ch) {
                int nb = kid * 32 + (((ch + kid) & 7) << 2);  // XOR-swizzle: kid*32 alone aliases banks
                float4 pv[3], fv[3];
                #pragma unroll
                for (int jj = 0; jj < 3; ++jj) pv[jj] = *(const float4*)&pT[(j0 + jj) * LDST + nb];
                #pragma unroll
                for (int cc2 = 0; cc2 < 3; ++cc2) fv[cc2] = *(const float4*)&fT[(c0 + cc2) * LDST + nb];
                #pragma unroll
                for (int jj = 0; jj < 3; ++jj)
                    #pragma unroll
                    for (int cc2 = 0; cc2 < 3; ++cc2)
                        acc[jj][cc2] += dot4f(pv[jj], fv[cc2]);
            }
            #pragma unroll
            for (int jj = 0; jj < 3; ++jj)
                #pragma unroll
                for (int cc2 = 0; cc2 < 3; ++cc2)
                    part[tile * 72 + kid * 9 + jj * 3 + cc2] = acc[jj][cc2];
        }
        __syncthreads();

        // 5. 189 partials -> one contiguous 756B plain store into my own P area (no atomics)
        if (t < 189) {
            int j = t / 21, c = t - 21 * j;
            int tile = (j / 3) * 7 + (c / 3);
            int elem = (j % 3) * 3 + (c % 3);
            float s = 0.f;
            #pragma unroll
            for (int kid = 0; kid < 8; ++kid) s += part[tile * 72 + kid * 9 + elem];
            sys_store(&Pcur[(size_t)blk * PBLK + t], s);    // [j][c] contiguous
        }
        __syncthreads();                    // drain partial stores
        // 6. signal each valid target slot
        if (t < 9) {
            int ky = cy + t / 3 - 1, kx = cx + (t % 3) - 1;
            if (ky >= 0 && ky < NKG && kx >= 0 && kx < NKG)
                __hip_atomic_fetch_add(cc + (size_t)(b * NK + ky * NKG + kx) * CPAD, 1u,
                                       __ATOMIC_RELAXED, __HIP_MEMORY_SCOPE_SYSTEM);
        }

        // 7. OWNER: wait for all my contributors' gen-g partials
        if (t == 0) {
            const unsigned* p = cc + (size_t)slot * CPAD;
            unsigned tgt = g * (unsigned)cnt_k;
            unsigned long long t0 = __builtin_amdgcn_s_memrealtime();
            while (sys_loadu(p) < tgt) {
                __builtin_amdgcn_s_sleep(2);
                if (__builtin_amdgcn_s_memrealtime() - t0 > 10000000ull) break;  // fail clean
            }
        }
        __syncthreads();

        // 8. gather contributors' partials (each 21-float run coalesced) into LDS
        if (t < 189) {
            int j = t / 21, c = t - 21 * j;
            int my = cy + j / 3 - 1, mx = cx + (j % 3) - 1;
            float v = 0.0f;
            if (my >= 0 && my < NKG && mx >= 0 && mx < NKG) {
                int mblk = b * NK + my * NKG + mx;
                // my slot's relative index inside contributor m's 3x3 is 8 - j
                v = sys_load(&Pcur[(size_t)mblk * PBLK + (8 - j) * NCS + c]);
            }
            part[j * NCS + c] = v;
        }
        __syncthreads();

        // 9. sum 9 -> S_g[my slot]
        if (t < NCS) {
            float s = 0.f;
            #pragma unroll
            for (int j = 0; j < 9; ++j) s += part[j * NCS + t];
            sys_store(&Snew[(size_t)slot * NCS + t], s);
        }
        __syncthreads();                    // drain S_g stores
        // 10. publish (single writer, plain store)
        if (t == 0) sys_storeu(rc + (size_t)slot * CPAD, g + 1);
    }

    // ---- final E-step (uses S_9, parity 1) + dense [B,N,K] output ----
    wait_rc(rc, 10u, b, cy, cx, t);
    stage_neigh(Sbuf + SB, b, cy, cx, t, sM, rqs);
    {
        float p[9];
        e_step_lds(f, sM, rqs, p);
        #pragma unroll
        for (int j = 0; j < 9; ++j) pT[j * LDST + t] = p[j];
    }
    __syncthreads();

    // Each wave writes full 256-float K-rows for 64 pixels: lane covers k = 4*ln .. 4*ln+3.
    // Nontemporal: 268 MB write-once, keep it out of L2.
    int wv = t >> 6, ln = t & 63;
    int j4[4];
    #pragma unroll
    for (int q = 0; q < 4; ++q) {
        int k = 4 * ln + q;
        int ky = k >> 4, kx = k & 15;
        int dy = ky - cy, dx = kx - cx;
        j4[q] = (dy >= -1 && dy <= 1 && dx >= -1 && dx <= 1) ? (dy + 1) * 3 + (dx + 1) : -1;
    }
    for (int i = 0; i < 64; ++i) {
        int pix = wv * 64 + i;
        int py = pix >> 4, px = pix & 15;
        int np = (cy * CELLSZ + py) * WIMG + cx * CELLSZ + px;
        nfloat4 o;
        o.x = (j4[0] >= 0) ? pT[j4[0] * LDST + pix] : 0.0f;
        o.y = (j4[1] >= 0) ? pT[j4[1] * LDST + pix] : 0.0f;
        o.z = (j4[2] >= 0) ? pT[j4[2] * LDST + pix] : 0.0f;
        o.w = (j4[3] >= 0) ? pT[j4[3] * LDST + pix] : 0.0f;
        size_t rowoff = ((size_t)(b * NPIX + np)) * (size_t)NK;
        __builtin_nontemporal_store(o, (nfloat4*)(out + rowoff + 4 * ln));
    }
}

// ---------------- fallback path (proven 11-kernel version, 546 us) ----------------

__device__ __forceinline__ void e_step_global(const float* f, int b, int cy, int cx,
                                              const float* __restrict__ Sprev, float p[9]) {
    float a[9];
    float amax = -1e30f;
    #pragma unroll
    for (int dy = -1; dy <= 1; ++dy) {
        #pragma unroll
        for (int dx = -1; dx <= 1; ++dx) {
            int j = (dy + 1) * 3 + (dx + 1);
            int ky = cy + dy, kx = cx + dx;
            if (ky >= 0 && ky < NKG && kx >= 0 && kx < NKG) {
                const float* sp = Sprev + ((size_t)(b * NK + ky * NKG + kx)) * NCS;
                float dots = 0.f, ssq = 0.f;
                #pragma unroll
                for (int c = 0; c < NC; ++c) {
                    float sv = sp[c];
                    dots = fmaf(f[c], sv, dots);
                    ssq  = fmaf(sv, sv, ssq);
                }
                float col = fmaxf(sp[NC], 1e-12f);
                float r = 1.0f / col;
                a[j] = 2.0f * r * dots - (r * r) * ssq;
                amax = fmaxf(amax, a[j]);
            } else {
                a[j] = -1e30f;
            }
        }
    }
    float esum = 0.f;
    #pragma unroll
    for (int j = 0; j < 9; ++j) {
        float e = (a[j] > -1e29f) ? __expf(a[j] - amax) : 0.0f;
        p[j] = e;
        esum += e;
    }
    float inv = 1.0f / esum;
    #pragma unroll
    for (int j = 0; j < 9; ++j) p[j] *= inv;
}

__global__ __launch_bounds__(256, 4) void k_init(const float* __restrict__ feat,
                                                 float* __restrict__ S0,
                                                 float* __restrict__ S1) {
    __shared__ float fT[NC * LDST];
    int blk = blockIdx.x;
    int b = blk >> 8, k0 = blk & 255;
    int cy = k0 >> 4, cx = k0 & 15;
    int t = threadIdx.x;
    int ly = t >> 4, lx = t & 15;
    int n = (cy * CELLSZ + ly) * WIMG + cx * CELLSZ + lx;
    float f[NC];
    load_feat(feat, b, n, f);
    #pragma unroll
    for (int c = 0; c < NC; ++c) fT[c * LDST + t] = f[c];
    __syncthreads();
    if (t < NCS) {
        float s;
        if (t == NC) {
            s = 256.0f;
        } else {
            s = 0.f;
            const float4* row = (const float4*)&fT[t * LDST];
            #pragma unroll 4
            for (int i = 0; i < 64; ++i) { float4 v = row[i]; s += v.x + v.y + v.z + v.w; }
        }
        size_t off = ((size_t)(b * NK + k0)) * NCS + t;
        S0[off] = s;
        S1[off] = 0.0f;
    }
}

__global__ __launch_bounds__(256, 4) void k_em(const float* __restrict__ feat,
                                               const float* __restrict__ Sprev,
                                               float* __restrict__ Snext,
                                               float* __restrict__ Szero) {
    __shared__ float fT[NCS * LDST];
    __shared__ float pT[9 * LDST];
    __shared__ float part[21 * 8 * 9];
    int blk = blockIdx.x;
    int b = blk >> 8, k0 = blk & 255;
    int cy = k0 >> 4, cx = k0 & 15;
    int t = threadIdx.x;
    int ly = t >> 4, lx = t & 15;
    int n = (cy * CELLSZ + ly) * WIMG + cx * CELLSZ + lx;
    float f[NC];
    load_feat(feat, b, n, f);
    #pragma unroll
    for (int c = 0; c < NC; ++c) fT[c * LDST + t] = f[c];
    fT[NC * LDST + t] = 1.0f;
    float p[9];
    e_step_global(f, b, cy, cx, Sprev, p);
    #pragma unroll
    for (int j = 0; j < 9; ++j) pT[j * LDST + t] = p[j];
    __syncthreads();

    if (t < 168) {
        int tile = t >> 3, kid = t & 7;
        int j0 = (tile / 7) * 3, c0 = (tile % 7) * 3;
        float acc[3][3] = {};
        #pragma unroll
        for (int ch = 0; ch < 8; ++ch) {
            int nb = kid * 32 + (((ch + kid) & 7) << 2);
            float4 pv[3], fv[3];
            #pragma unroll
            for (int jj = 0; jj < 3; ++jj) pv[jj] = *(const float4*)&pT[(j0 + jj) * LDST + nb];
            #pragma unroll
            for (int cc2 = 0; cc2 < 3; ++cc2) fv[cc2] = *(const float4*)&fT[(c0 + cc2) * LDST + nb];
            #pragma unroll
            for (int jj = 0; jj < 3; ++jj)
                #pragma unroll
                for (int cc2 = 0; cc2 < 3; ++cc2)
                    acc[jj][cc2] += dot4f(pv[jj], fv[cc2]);
        }
        #pragma unroll
        for (int jj = 0; jj < 3; ++jj)
            #pragma unroll
            for (int cc2 = 0; cc2 < 3; ++cc2)
                part[tile * 72 + kid * 9 + jj * 3 + cc2] = acc[jj][cc2];
    }
    __syncthreads();
    if (t < 189) {
        int j = t / 21, c = t % 21;
        int tile = (j / 3) * 7 + (c / 3);
        int elem = (j % 3) * 3 + (c % 3);
        float s = 0.f;
        #pragma unroll
        for (int kid = 0; kid < 8; ++kid) s += part[tile * 72 + kid * 9 + elem];
        int ky = cy + (j / 3) - 1, kx = cx + (j % 3) - 1;
        if (ky >= 0 && ky < NKG && kx >= 0 && kx < NKG)
            atomicAdd(&Snext[((size_t)(b * NK + ky * NKG + kx)) * NCS + c], s);
    }
    if (t < NCS) Szero[((size_t)(b * NK + k0)) * NCS + t] = 0.0f;
}

__global__ __launch_bounds__(256, 4) void k_final(const float* __restrict__ feat,
                                                  const float* __restrict__ Sprev,
                                                  float* __restrict__ out) {
    __shared__ float pT[9 * LDST];
    int blk = blockIdx.x;
    int b = blk >> 8, k0 = blk & 255;
    int cy = k0 >> 4, cx = k0 & 15;
    int t = threadIdx.x;
    int ly = t >> 4, lx = t & 15;
    int n = (cy * CELLSZ + ly) * WIMG + cx * CELLSZ + lx;
    float f[NC];
    load_feat(feat, b, n, f);
    float p[9];
    e_step_global(f, b, cy, cx, Sprev, p);
    #pragma unroll
    for (int j = 0; j < 9; ++j) pT[j * LDST + t] = p[j];
    __syncthreads();

    int wv = t >> 6, ln = t & 63;
    int j4[4];
    #pragma unroll
    for (int q = 0; q < 4; ++q) {
        int k = 4 * ln + q;
        int ky = k >> 4, kx = k & 15;
        int dy = ky - cy, dx = kx - cx;
        j4[q] = (dy >= -1 && dy <= 1 && dx >= -1 && dx <= 1) ? (dy + 1) * 3 + (dx + 1) : -1;
    }
    for (int i = 0; i < 64; ++i) {
        int pix = wv * 64 + i;
        int py = pix >> 4, px = pix & 15;
        int np = (cy * CELLSZ + py) * WIMG + cx * CELLSZ + px;
        float4 o;
        o.x = (j4[0] >= 0) ? pT[j4[0] * LDST + pix] : 0.0f;
        o.y = (j4[1] >= 0) ? pT[j4[1] * LDST + pix] : 0.0f;
        o.z = (j4[2] >= 0) ? pT[j4[2] * LDST + pix] : 0.0f;
        o.w = (j4[3] >= 0) ? pT[j4[3] * LDST + pix] : 0.0f;
        size_t rowoff = ((size_t)(b * NPIX + np)) * (size_t)NK;
        *(float4*)(out + rowoff + 4 * ln) = o;
    }
}

extern "C" void kernel_launch(void* const* d_in, const int* in_sizes, int n_in,
                              void* d_out, int out_size, void* d_ws, size_t ws_size,
                              hipStream_t stream) {
    (void)in_sizes; (void)n_in; (void)out_size; (void)ws_size;
    const float* feat = (const float*)d_in[0];
    // d_in[1..4] (valid_spixel, adjust_dist, spixel_init, iter_EM) are implied by geometry.
    float* out = (float*)d_out;
    // Workspace layout:
    //   [0, 172KB)      Sbuf[2][B*K][21]
    //   [256KB, 768KB)  rc lines (1024 x 256B) then cc lines (1024 x 256B)
    //   [1MB, ~2.6MB)   Pp[2][NBLK][189]
    float* Sbuf = (float*)d_ws;
    unsigned* rc = (unsigned*)((char*)d_ws + (256 << 10));
    unsigned* cc = (unsigned*)((char*)d_ws + (256 << 10) + (size_t)NBLK * CPAD * 4);
    float* Pp = (float*)((char*)d_ws + (1 << 20));

    dim3 grid(NBLK), block(256);
    k_zero_ctr<<<8, 256, 0, stream>>>(rc);   // zeros rc then cc (contiguous 2048 lines)

    void* args[] = { (void*)&feat, (void*)&Sbuf, (void*)&Pp, (void*)&rc, (void*)&cc, (void*)&out };
    hipError_t err = hipLaunchCooperativeKernel((const void*)k_fused, grid, block,
                                                (void**)args, 0u, stream);
    if (err != hipSuccess) {
        // Fallback: proven multi-kernel path (identical math, 546 us).
        // Needs 3 plain buffers; reuse the P area (far from Sbuf/ctrs).
        float* b0 = Pp;
        float* b1 = b0 + SB;
        float* b2 = b1 + SB;
        k_init<<<grid, block, 0, stream>>>(feat, b0, b1);
        float* bufs[3] = { b0, b1, b2 };
        for (int i = 1; i <= 9; ++i) {
            k_em<<<grid, block, 0, stream>>>(feat, bufs[(i - 1) % 3], bufs[i % 3], bufs[(i + 1) % 3]);
        }
        k_final<<<grid, block, 0, stream>>>(feat, bufs[0], out);
    }
}

// Round 8
// 612.959 us; speedup vs baseline: 1.0312x; 1.0312x over previous
//
#include <hip/hip_runtime.h>

// SSN superpixel EM, MI355X. B=4, H=W=256, C=20, KG=16 (K=256), CELL=16, 10 EM iters.
// Exploits 9-neighborhood sparsity: posteriors are exactly 0 outside it (exp underflow).
// v8: v7's per-slot dataflow kernel, launched as a PLAIN kernel (no cooperative launch).
//   - v4..v7 timing: k_fused dur vs benched dur shows a constant ~290us gap -> the
//     hipLaunchCooperativeKernel call itself is the tax (graph-capture-hostile, serializing).
//   - Co-residency of all 1024 blocks is guaranteed by capacity: __launch_bounds__(256,4),
//     LDS 38.4KB -> exactly 4 blocks/CU; grid = 1024 = 4 x 256 CU. All blocks must be
//     resident before any can pass its first wait (mutual dependence), and capacity admits
//     them all. Spin timeouts turn any violated assumption into a clean numeric failure.
//   - v7 structure unchanged: no stats atomics; each block writes 189 partials contiguously;
//     slot owner gathers+sums+publishes rc; consumers poll 9 rc words; parity double-buffer.

#define NBATCH 4
#define WIMG   256
#define NC     20      // feature channels
#define NCS    21      // channels + colsum slot
#define NKG    16
#define NK     256
#define NPIX   65536
#define CELLSZ 16
#define LDST   260     // LDS row stride (floats), 16B-aligned rows
#define NBLK   (NBATCH * NK)   // 1024 blocks, 4/CU
#define CPAD   64      // counter padding in u32 words (256 B per counter line)
#define SB     ((size_t)NBATCH * NK * NCS)   // one S buffer: 21504 floats
#define PBLK   (9 * NCS)                     // 189 partials per block

typedef float nfloat4 __attribute__((ext_vector_type(4)));  // native vec for nontemporal builtin

__device__ __forceinline__ float dot4f(const float4 a, const float4 b) {
    return fmaf(a.x, b.x, fmaf(a.y, b.y, fmaf(a.z, b.z, a.w * b.w)));
}

// SYSTEM scope: sc0+sc1 -> bypass L1 and (non-cross-XCD-coherent) L2.
__device__ __forceinline__ float sys_load(const float* p) {
    return __hip_atomic_load(p, __ATOMIC_RELAXED, __HIP_MEMORY_SCOPE_SYSTEM);
}
__device__ __forceinline__ void sys_store(float* p, float v) {
    __hip_atomic_store(p, v, __ATOMIC_RELAXED, __HIP_MEMORY_SCOPE_SYSTEM);
}
__device__ __forceinline__ unsigned sys_loadu(const unsigned* p) {
    return __hip_atomic_load(p, __ATOMIC_RELAXED, __HIP_MEMORY_SCOPE_SYSTEM);
}
__device__ __forceinline__ void sys_storeu(unsigned* p, unsigned v) {
    __hip_atomic_store(p, v, __ATOMIC_RELAXED, __HIP_MEMORY_SCOPE_SYSTEM);
}

// Consumers: poll rc of the 9 neighbor slots for >= tgt (rc[k]=g+1 means S_g[k] ready).
__device__ __forceinline__ void wait_rc(const unsigned* rc, unsigned tgt,
                                        int b, int cy, int cx, int t) {
    if (t < 9) {
        int ky = cy + t / 3 - 1, kx = cx + (t % 3) - 1;
        if (ky >= 0 && ky < NKG && kx >= 0 && kx < NKG) {
            const unsigned* p = rc + (size_t)(b * NK + ky * NKG + kx) * CPAD;
            unsigned long long t0 = __builtin_amdgcn_s_memrealtime();
            while (sys_loadu(p) < tgt) {
                __builtin_amdgcn_s_sleep(2);
                if (__builtin_amdgcn_s_memrealtime() - t0 > 10000000ull) break;  // fail clean
            }
        }
    }
    __syncthreads();
}

__device__ __forceinline__ void load_feat(const float* __restrict__ feat, int b, int n, float f[NC]) {
    const float4* fp = (const float4*)(feat + ((size_t)b * NPIX + n) * NC);  // 80B/pixel, 16B aligned
    #pragma unroll
    for (int i = 0; i < 5; ++i) {
        float4 v = fp[i];
        f[4 * i + 0] = v.x; f[4 * i + 1] = v.y; f[4 * i + 2] = v.z; f[4 * i + 3] = v.w;
    }
}

// Stage this block's 3x3 neighborhood stats into LDS; derive per-neighbor uniform
// coefficients so per-lane a[j] = rqs[j].x * dot(f, S_j) + rqs[j].y.
__device__ __forceinline__ void stage_neigh(const float* __restrict__ Sprev, int b, int cy, int cx,
                                            int t, float (*sM)[24], float (*rqs)[2]) {
    if (t < 189) {
        int j = t / 21, c = t - 21 * j;
        int ky = cy + j / 3 - 1, kx = cx + (j % 3) - 1;
        float v = 0.0f;
        if (ky >= 0 && ky < NKG && kx >= 0 && kx < NKG)
            v = sys_load(&Sprev[((size_t)(b * NK + ky * NKG + kx)) * NCS + c]);
        sM[j][c] = v;
    }
    __syncthreads();
    if (t < 9) {
        int ky = cy + t / 3 - 1, kx = cx + (t % 3) - 1;
        bool ok = (ky >= 0 && ky < NKG && kx >= 0 && kx < NKG);
        float ssq = 0.f;
        #pragma unroll
        for (int cq = 0; cq < 5; ++cq) {
            float4 sv = *((const float4*)&sM[t][4 * cq]);
            ssq += dot4f(sv, sv);
        }
        float r = 1.0f / fmaxf(sM[t][NC], 1e-12f);
        // -dist + feat_sq = 2*f.mean - ||mean||^2 ; invalid neighbors pinned to -1e30
        rqs[t][0] = ok ? 2.0f * r : 0.0f;
        rqs[t][1] = ok ? -(r * r) * ssq : -1e30f;
    }
    __syncthreads();
}

// Per-pixel softmax over 9 neighbors from staged LDS stats.
__device__ __forceinline__ void e_step_lds(const float f[NC], const float (*sM)[24],
                                           const float (*rqs)[2], float p[9]) {
    float a[9];
    float amax = -1e30f;
    #pragma unroll
    for (int j = 0; j < 9; ++j) {
        float dots = 0.f;
        #pragma unroll
        for (int cq = 0; cq < 5; ++cq) {
            float4 sv = *((const float4*)&sM[j][4 * cq]);   // ds_read_b128, broadcast
            dots = fmaf(f[4 * cq + 0], sv.x,
                   fmaf(f[4 * cq + 1], sv.y,
                   fmaf(f[4 * cq + 2], sv.z,
                   fmaf(f[4 * cq + 3], sv.w, dots))));
        }
        float2 rv = *((const float2*)rqs[j]);
        a[j] = fmaf(rv.x, dots, rv.y);
        amax = fmaxf(amax, a[j]);
    }
    float esum = 0.f;
    #pragma unroll
    for (int j = 0; j < 9; ++j) {
        float e = (a[j] > -1e29f) ? __expf(a[j] - amax) : 0.0f;
        p[j] = e;
        esum += e;
    }
    float inv = 1.0f / esum;
    #pragma unroll
    for (int j = 0; j < 9; ++j) p[j] *= inv;
}

#define NZLINES (2 * NBLK)   // rc lines + cc lines
__global__ void k_zero_ctr(unsigned* ctr) {
    int i = blockIdx.x * 256 + threadIdx.x;
    if (i < NZLINES) ctr[(size_t)i * CPAD] = 0u;   // only word 0 of each line is used
}

// Persistent fused kernel: init mean + 9 EM iterations + final dense output.
// Grid must be exactly NBATCH*NK = 1024 blocks; co-residency by capacity (4/CU x 256 CU).
__global__ __launch_bounds__(256, 4) void k_fused(const float* __restrict__ feat,
                                                  float* __restrict__ Sbuf,   // [2][B*K][21]
                                                  float* __restrict__ Pp,     // [2][NBLK][9][21]
                                                  unsigned* __restrict__ rc,  // [NBLK] padded
                                                  unsigned* __restrict__ cc,  // [NBLK] padded
                                                  float* __restrict__ out) {
    __shared__ float fT[NCS * LDST];     // [c][n], row 20 = ones (colsum)
    __shared__ float pT[9 * LDST];       // [j][n]
    __shared__ float part[21 * 8 * 9];   // [tile][kid][3x3]; reused as gather buf [9][21]
    __shared__ float sM[9][24];          // staged neighbor stats, 16B-aligned rows
    __shared__ float rqs[9][2];          // per-neighbor (2/col, -||S||^2/col^2)

    int blk = blockIdx.x;
    int b = blk >> 8, k0 = blk & 255;
    int cy = k0 >> 4, cx = k0 & 15;
    int t = threadIdx.x;
    int ly = t >> 4, lx = t & 15;
    int n = (cy * CELLSZ + ly) * WIMG + cx * CELLSZ + lx;
    int slot = b * NK + k0;
    int cnt_k = (1 + (cy > 0) + (cy < NKG - 1)) * (1 + (cx > 0) + (cx < NKG - 1));

    float f[NC];
    load_feat(feat, b, n, f);
    #pragma unroll
    for (int c = 0; c < NC; ++c) fT[c * LDST + t] = f[c];
    fT[NC * LDST + t] = 1.0f;
    __syncthreads();

    // ---- init: S_0 = per-cell feature sums (col = 256), into Sbuf parity 0 ----
    if (t < NCS) {
        float s;
        if (t == NC) {
            s = 256.0f;
        } else {
            s = 0.f;
            const float4* row = (const float4*)&fT[t * LDST];
            #pragma unroll 4
            for (int i = 0; i < 64; ++i) { float4 v = row[i]; s += v.x + v.y + v.z + v.w; }
        }
        sys_store(&Sbuf[(size_t)slot * NCS + t], s);
    }
    __syncthreads();                        // drain S_0 stores
    if (t == 0) sys_storeu(rc + (size_t)slot * CPAD, 1u);   // S_0 ready

    for (unsigned g = 1; g <= 9; ++g) {
        const float* Sprev = Sbuf + (size_t)((g - 1) & 1) * SB;
        float*       Snew  = Sbuf + (size_t)(g & 1) * SB;
        float*       Pcur  = Pp + (size_t)(g & 1) * NBLK * PBLK;

        // 1. wait: my 3x3 S_{g-1} published
        wait_rc(rc, g, b, cy, cx, t);
        // 2. stage + coefficients
        stage_neigh(Sprev, b, cy, cx, t, sM, rqs);

        // 3. E-step
        float p[9];
        e_step_lds(f, sM, rqs, p);
        #pragma unroll
        for (int j = 0; j < 9; ++j) pT[j * LDST + t] = p[j];
        __syncthreads();

        // 4. Tiled [9x256]x[256x21] reduction: 21 (3j x 3c) tiles x 8 K-splits = 168 threads.
        if (t < 168) {
            int tile = t >> 3, kid = t & 7;
            int j0 = (tile / 7) * 3, c0 = (tile % 7) * 3;
            float acc[3][3] = {};
            #pragma unroll
            for (int ch = 0; ch < 8; ++ch) {
                int nb = kid * 32 + (((ch + kid) & 7) << 2);  // XOR-swizzle: kid*32 alone aliases banks
                float4 pv[3], fv[3];
                #pragma unroll
                for (int jj = 0; jj < 3; ++jj) pv[jj] = *(const float4*)&pT[(j0 + jj) * LDST + nb];
                #pragma unroll
                for (int cc2 = 0; cc2 < 3; ++cc2) fv[cc2] = *(const float4*)&fT[(c0 + cc2) * LDST + nb];
                #pragma unroll
                for (int jj = 0; jj < 3; ++jj)
                    #pragma unroll
                    for (int cc2 = 0; cc2 < 3; ++cc2)
                        acc[jj][cc2] += dot4f(pv[jj], fv[cc2]);
            }
            #pragma unroll
            for (int jj = 0; jj < 3; ++jj)
                #pragma unroll
                for (int cc2 = 0; cc2 < 3; ++cc2)
                    part[tile * 72 + kid * 9 + jj * 3 + cc2] = acc[jj][cc2];
        }
        __syncthreads();

        // 5. 189 partials -> one contiguous 756B plain store into my own P area (no atomics)
        if (t < 189) {
            int j = t / 21, c = t - 21 * j;
            int tile = (j / 3) * 7 + (c / 3);
            int elem = (j % 3) * 3 + (c % 3);
            float s = 0.f;
            #pragma unroll
            for (int kid = 0; kid < 8; ++kid) s += part[tile * 72 + kid * 9 + elem];
            sys_store(&Pcur[(size_t)blk * PBLK + t], s);    // [j][c] contiguous
        }
        __syncthreads();                    // drain partial stores
        // 6. signal each valid target slot
        if (t < 9) {
            int ky = cy + t / 3 - 1, kx = cx + (t % 3) - 1;
            if (ky >= 0 && ky < NKG && kx >= 0 && kx < NKG)
                __hip_atomic_fetch_add(cc + (size_t)(b * NK + ky * NKG + kx) * CPAD, 1u,
                                       __ATOMIC_RELAXED, __HIP_MEMORY_SCOPE_SYSTEM);
        }

        // 7. OWNER: wait for all my contributors' gen-g partials
        if (t == 0) {
            const unsigned* p = cc + (size_t)slot * CPAD;
            unsigned tgt = g * (unsigned)cnt_k;
            unsigned long long t0 = __builtin_amdgcn_s_memrealtime();
            while (sys_loadu(p) < tgt) {
                __builtin_amdgcn_s_sleep(2);
                if (__builtin_amdgcn_s_memrealtime() - t0 > 10000000ull) break;  // fail clean
            }
        }
        __syncthreads();

        // 8. gather contributors' partials (each 21-float run coalesced) into LDS
        if (t < 189) {
            int j = t / 21, c = t - 21 * j;
            int my = cy + j / 3 - 1, mx = cx + (j % 3) - 1;
            float v = 0.0f;
            if (my >= 0 && my < NKG && mx >= 0 && mx < NKG) {
                int mblk = b * NK + my * NKG + mx;
                // my slot's relative index inside contributor m's 3x3 is 8 - j
                v = sys_load(&Pcur[(size_t)mblk * PBLK + (8 - j) * NCS + c]);
            }
            part[j * NCS + c] = v;
        }
        __syncthreads();

        // 9. sum 9 -> S_g[my slot]
        if (t < NCS) {
            float s = 0.f;
            #pragma unroll
            for (int j = 0; j < 9; ++j) s += part[j * NCS + t];
            sys_store(&Snew[(size_t)slot * NCS + t], s);
        }
        __syncthreads();                    // drain S_g stores
        // 10. publish (single writer, plain store)
        if (t == 0) sys_storeu(rc + (size_t)slot * CPAD, g + 1);
    }

    // ---- final E-step (uses S_9, parity 1) + dense [B,N,K] output ----
    wait_rc(rc, 10u, b, cy, cx, t);
    stage_neigh(Sbuf + SB, b, cy, cx, t, sM, rqs);
    {
        float p[9];
        e_step_lds(f, sM, rqs, p);
        #pragma unroll
        for (int j = 0; j < 9; ++j) pT[j * LDST + t] = p[j];
    }
    __syncthreads();

    // Each wave writes full 256-float K-rows for 64 pixels: lane covers k = 4*ln .. 4*ln+3.
    // Nontemporal: 268 MB write-once, keep it out of L2.
    int wv = t >> 6, ln = t & 63;
    int j4[4];
    #pragma unroll
    for (int q = 0; q < 4; ++q) {
        int k = 4 * ln + q;
        int ky = k >> 4, kx = k & 15;
        int dy = ky - cy, dx = kx - cx;
        j4[q] = (dy >= -1 && dy <= 1 && dx >= -1 && dx <= 1) ? (dy + 1) * 3 + (dx + 1) : -1;
    }
    for (int i = 0; i < 64; ++i) {
        int pix = wv * 64 + i;
        int py = pix >> 4, px = pix & 15;
        int np = (cy * CELLSZ + py) * WIMG + cx * CELLSZ + px;
        nfloat4 o;
        o.x = (j4[0] >= 0) ? pT[j4[0] * LDST + pix] : 0.0f;
        o.y = (j4[1] >= 0) ? pT[j4[1] * LDST + pix] : 0.0f;
        o.z = (j4[2] >= 0) ? pT[j4[2] * LDST + pix] : 0.0f;
        o.w = (j4[3] >= 0) ? pT[j4[3] * LDST + pix] : 0.0f;
        size_t rowoff = ((size_t)(b * NPIX + np)) * (size_t)NK;
        __builtin_nontemporal_store(o, (nfloat4*)(out + rowoff + 4 * ln));
    }
}

extern "C" void kernel_launch(void* const* d_in, const int* in_sizes, int n_in,
                              void* d_out, int out_size, void* d_ws, size_t ws_size,
                              hipStream_t stream) {
    (void)in_sizes; (void)n_in; (void)out_size; (void)ws_size;
    const float* feat = (const float*)d_in[0];
    // d_in[1..4] (valid_spixel, adjust_dist, spixel_init, iter_EM) are implied by geometry.
    float* out = (float*)d_out;
    // Workspace layout:
    //   [0, 172KB)      Sbuf[2][B*K][21]
    //   [256KB, 768KB)  rc lines (1024 x 256B) then cc lines (1024 x 256B)
    //   [1MB, ~2.6MB)   Pp[2][NBLK][189]
    float* Sbuf = (float*)d_ws;
    unsigned* rc = (unsigned*)((char*)d_ws + (256 << 10));
    unsigned* cc = (unsigned*)((char*)d_ws + (256 << 10) + (size_t)NBLK * CPAD * 4);
    float* Pp = (float*)((char*)d_ws + (1 << 20));

    dim3 grid(NBLK), block(256);
    k_zero_ctr<<<8, 256, 0, stream>>>(rc);   // zeros rc then cc (contiguous 2048 lines)
    k_fused<<<grid, block, 0, stream>>>(feat, Sbuf, Pp, rc, cc, out);
}